// Round 1
// baseline (169.234 us; speedup 1.0000x reference)
//
#include <hip/hip_runtime.h>
#include <math.h>

// Problem constants (from reference)
#define BB   64     // batch
#define WW   128    // node feature dim (input width)
#define FF   64     // n nodes (features axis)
#define HH   4      // heads
#define OW   128    // out width per head
#define HO   (HH*OW)   // 512
#define NEG  0.2f

// ---------------------------------------------------------------------------
// Kernel A: projections.  proj rows 0..511 = fs, 512..1023 = fd.
//   fs[b,f,ho] = sum_w x[b,w,f] * W_src[ho,w] + b_src[ho]   (fd likewise)
// Grid: 64 b * 32 row-tiles(32 rows each)?  -> chosen: 64 b * 16 tiles of 64
// rows, K split into two 64-wide phases to keep LDS ~34 KB.
// Block 256 threads: 16x16 thread grid, 4x4 register tile (f x r).
// ---------------------------------------------------------------------------
__global__ __launch_bounds__(256) void gat_proj(
    const float* __restrict__ x,     // [B][W][F]
    const float* __restrict__ Wsrc,  // [512][128]
    const float* __restrict__ bsrc,  // [512]
    const float* __restrict__ Wdst,  // [512][128]
    const float* __restrict__ bdst,  // [512]
    float* __restrict__ fs,          // [B][F][512]
    float* __restrict__ fd)          // [B][F][512]
{
    __shared__ float x_lds[64 * FF];      // [w_local][f]  16 KB
    __shared__ float w_lds[64 * 68];      // [r][w_local], stride 68 pad  17 KB

    const int tid  = threadIdx.x;
    const int b    = blockIdx.x >> 4;
    const int tile = blockIdx.x & 15;
    const int rowbase = tile * 64;        // row in concatenated [Wsrc;Wdst]

    const float* xb = x + (size_t)b * (WW * FF);

    const int tx = tid & 15, ty = tid >> 4;
    const int f0 = tx * 4,   r0 = ty * 4;

    float acc[4][4] = {};   // acc[ff][rr]

    for (int kp = 0; kp < 2; ++kp) {
        // ---- load x chunk: w in [kp*64, kp*64+64), contiguous 16 KB ----
        const float* xsrc = xb + (size_t)kp * 64 * FF;
        #pragma unroll
        for (int p = 0; p < 4; ++p) {
            int e = (p * 256 + tid) * 4;          // float index < 4096
            *(float4*)&x_lds[e] = *(const float4*)&xsrc[e];
        }
        // ---- load W tile: 64 rows x 64 cols ----
        #pragma unroll
        for (int p = 0; p < 4; ++p) {
            int e4 = p * 256 + tid;               // float4 index < 1024
            int r  = e4 >> 4;
            int w  = (e4 & 15) * 4;
            int R  = rowbase + r;
            const float* row = (R < HO) ? (Wsrc + (size_t)R * WW)
                                        : (Wdst + (size_t)(R - HO) * WW);
            *(float4*)&w_lds[r * 68 + w] = *(const float4*)&row[kp * 64 + w];
        }
        __syncthreads();

        // ---- accumulate over 64 w ----
        #pragma unroll
        for (int w0 = 0; w0 < 64; w0 += 4) {
            float4 wv[4];
            #pragma unroll
            for (int rr = 0; rr < 4; ++rr)
                wv[rr] = *(const float4*)&w_lds[(r0 + rr) * 68 + w0];
            #pragma unroll
            for (int wwi = 0; wwi < 4; ++wwi) {
                float4 xv = *(const float4*)&x_lds[(w0 + wwi) * FF + f0];
                float xf[4] = {xv.x, xv.y, xv.z, xv.w};
                #pragma unroll
                for (int rr = 0; rr < 4; ++rr) {
                    float wf = ((const float*)&wv[rr])[wwi];
                    #pragma unroll
                    for (int ff = 0; ff < 4; ++ff)
                        acc[ff][rr] = fmaf(xf[ff], wf, acc[ff][rr]);
                }
            }
        }
        __syncthreads();
    }

    // ---- epilogue: add bias, store float4 per f-row ----
    const int R0 = rowbase + r0;
    const bool is_src = (rowbase < HO);
    const float* bias = is_src ? bsrc : bdst;
    float* dst = is_src ? fs : fd;
    const int roff = is_src ? R0 : (R0 - HO);
    float b0 = bias[roff + 0], b1 = bias[roff + 1],
          b2 = bias[roff + 2], b3 = bias[roff + 3];
    #pragma unroll
    for (int ff = 0; ff < 4; ++ff) {
        int f = f0 + ff;
        float4 o;
        o.x = acc[ff][0] + b0;
        o.y = acc[ff][1] + b1;
        o.z = acc[ff][2] + b2;
        o.w = acc[ff][3] + b3;
        *(float4*)&dst[((size_t)b * FF + f) * HO + roff] = o;
    }
}

// ---------------------------------------------------------------------------
// Kernel B: fused scores + edge softmax + aggregation + head-mean + transpose
// Block per (b, j): 256 threads = 4 waves, wave h handles head h.
// Lane owns d0=2*lane, d0+1 of the OUTW=128 dim.
//   score[h][i] = sum_d lrelu(fs[b,i,h,d] + fd[b,j,h,d]) * attn[h,d]
//   a = softmax_i(score);  out[b,d,j] = 0.25 * sum_h sum_i a[i]*fs[b,i,h,d]
// ---------------------------------------------------------------------------
__global__ __launch_bounds__(256) void gat_attn(
    const float* __restrict__ fs,    // [B][F][512]
    const float* __restrict__ fd,    // [B][F][512]
    const float* __restrict__ attn,  // [H][OW]
    float* __restrict__ out)         // [B][OW][F]
{
    const int b    = blockIdx.x >> 6;
    const int j    = blockIdx.x & 63;
    const int h    = threadIdx.x >> 6;
    const int lane = threadIdx.x & 63;
    const int d0   = lane * 2;

    const float* fsb = fs + (size_t)b * FF * HO;
    float2 fdv = *(const float2*)&fd[((size_t)b * FF + j) * HO + h * OW + d0];
    float2 av  = *(const float2*)&attn[h * OW + d0];

    __shared__ float s_out[HH][OW];

    // ---- phase 1: scores (lane i ends holding score for source i) ----
    float myscore = 0.0f;
    for (int i = 0; i < FF; ++i) {
        float2 fsv = *(const float2*)&fsb[(size_t)i * HO + h * OW + d0];
        float s0 = fsv.x + fdv.x;
        float s1 = fsv.y + fdv.y;
        float e0 = fmaxf(s0, NEG * s0);   // LeakyReLU
        float e1 = fmaxf(s1, NEG * s1);
        float p  = fmaf(e0, av.x, e1 * av.y);
        #pragma unroll
        for (int off = 32; off > 0; off >>= 1)
            p += __shfl_xor(p, off, 64);
        if (lane == i) myscore = p;
    }

    // ---- phase 2: softmax over i (64 lanes = 64 sources) ----
    float m = myscore;
    #pragma unroll
    for (int off = 32; off > 0; off >>= 1)
        m = fmaxf(m, __shfl_xor(m, off, 64));
    float ex = __expf(myscore - m);
    float ssum = ex;
    #pragma unroll
    for (int off = 32; off > 0; off >>= 1)
        ssum += __shfl_xor(ssum, off, 64);
    float a_mine = ex / ssum;

    // ---- phase 3: aggregation sum_i a[i] * fs[b,i,h,d] ----
    float acc0 = 0.0f, acc1 = 0.0f;
    for (int i = 0; i < FF; ++i) {
        float ai = __shfl(a_mine, i, 64);
        float2 fsv = *(const float2*)&fsb[(size_t)i * HO + h * OW + d0];
        acc0 = fmaf(ai, fsv.x, acc0);
        acc1 = fmaf(ai, fsv.y, acc1);
    }
    s_out[h][d0]     = acc0;
    s_out[h][d0 + 1] = acc1;
    __syncthreads();

    // ---- phase 4: head mean + transposed store out[b, d, j] ----
    if (threadIdx.x < OW) {
        int d = threadIdx.x;
        float o = 0.25f * (s_out[0][d] + s_out[1][d] + s_out[2][d] + s_out[3][d]);
        out[((size_t)b * OW + d) * FF + j] = o;
    }
}

// ---------------------------------------------------------------------------
extern "C" void kernel_launch(void* const* d_in, const int* in_sizes, int n_in,
                              void* d_out, int out_size, void* d_ws, size_t ws_size,
                              hipStream_t stream) {
    const float* x    = (const float*)d_in[0];
    const float* Wsrc = (const float*)d_in[1];
    const float* bsrc = (const float*)d_in[2];
    const float* Wdst = (const float*)d_in[3];
    const float* bdst = (const float*)d_in[4];
    const float* attn = (const float*)d_in[5];
    float* out = (float*)d_out;

    float* fs = (float*)d_ws;                       // [B][F][512]  8 MB
    float* fd = fs + (size_t)BB * FF * HO;          // [B][F][512]  8 MB

    gat_proj<<<BB * 16, 256, 0, stream>>>(x, Wsrc, bsrc, Wdst, bdst, fs, fd);
    gat_attn<<<BB * FF, 256, 0, stream>>>(fs, fd, attn, out);
}

// Round 2
// 130.891 us; speedup vs baseline: 1.2929x; 1.2929x over previous
//
#include <hip/hip_runtime.h>
#include <math.h>

#define BB 64
#define WW 128
#define FF 64
#define HH 4
#define OW 128
#define HO 512   // H*OW

// ---------------------------------------------------------------------------
// Kernel 1: projections, pure register-tiled, operands direct from L1/L2.
// Grid: 64 b x 16 row-tiles (64 rows of the 1024 concat [Wsrc;Wdst]).
// Block 128 thr: fx=t&7 (f0=8fx), ry=t>>3 (r0=4ry). 8f x 4r tile, K=128.
// Per 4k-chunk: 8 x-float4 (8 uniq addr/wave, broadcast) + 4 w-float4
// (16 uniq addr/wave) + 128 FMA. FMA-bound: floor ~7us.
// ---------------------------------------------------------------------------
__global__ __launch_bounds__(128) void gat_proj(
    const float* __restrict__ x,     // [B][W][F]
    const float* __restrict__ Wsrc,  // [512][128]
    const float* __restrict__ bsrc,
    const float* __restrict__ Wdst,
    const float* __restrict__ bdst,
    float* __restrict__ fs,          // [B][F][512]
    float* __restrict__ fd)
{
    const int b  = blockIdx.x >> 4;
    const int rt = blockIdx.x & 15;
    const bool is_src = rt < 8;
    const int roff = (rt & 7) * 64;          // row base within this matrix's 512

    const float* Wm  = is_src ? Wsrc : Wdst;
    const float* bm  = is_src ? bsrc : bdst;
    float*       dst = is_src ? fs   : fd;

    const int t  = threadIdx.x;
    const int f0 = (t & 7) * 8;
    const int r0 = (t >> 3) * 4;

    const float* xb    = x  + (size_t)b * (WW * FF);
    const float* wbase = Wm + (size_t)(roff + r0) * WW;

    float acc[8][4] = {};

    #pragma unroll 2
    for (int c = 0; c < 32; ++c) {
        const int k0 = c * 4;
        float4 xv0[4], xv1[4], wv[4];
        #pragma unroll
        for (int kk = 0; kk < 4; ++kk) {
            const float* xp = xb + (size_t)(k0 + kk) * FF + f0;
            xv0[kk] = *(const float4*)xp;
            xv1[kk] = *(const float4*)(xp + 4);
        }
        #pragma unroll
        for (int m = 0; m < 4; ++m)
            wv[m] = *(const float4*)(wbase + (size_t)m * WW + k0);
        #pragma unroll
        for (int kk = 0; kk < 4; ++kk) {
            #pragma unroll
            for (int m = 0; m < 4; ++m) {
                const float wf = ((const float*)&wv[m])[kk];
                #pragma unroll
                for (int ff = 0; ff < 4; ++ff)
                    acc[ff][m]     = fmaf(((const float*)&xv0[kk])[ff], wf, acc[ff][m]);
                #pragma unroll
                for (int ff = 0; ff < 4; ++ff)
                    acc[ff + 4][m] = fmaf(((const float*)&xv1[kk])[ff], wf, acc[ff + 4][m]);
            }
        }
    }

    float4 bv = *(const float4*)(bm + roff + r0);
    #pragma unroll
    for (int ff = 0; ff < 8; ++ff) {
        float4 o;
        o.x = acc[ff][0] + bv.x;
        o.y = acc[ff][1] + bv.y;
        o.z = acc[ff][2] + bv.z;
        o.w = acc[ff][3] + bv.w;
        *(float4*)&dst[((size_t)b * FF + f0 + ff) * HO + roff + r0] = o;
    }
}

// ---------------------------------------------------------------------------
// Kernel 2: fused scores + edge-softmax + aggregation per (b, h).
// Grid 256 = 64 b x 4 h. Block 256 thr.
// Scores: lrelu(s)*attn = A*s + B*|s| with A=0.6*attn, B=0.4*attn.
// (4i x 4j) register tile over d; fs/fd fragments direct from L1 (the
// block-wide working window per d-chunk is ~2 KB). No shuffles anywhere.
// Softmax column-parallel in LDS; aggregation (4j x 8d) tile over i.
// Writes per-head partial to ws2[b][h][d][j].
// ---------------------------------------------------------------------------
__global__ __launch_bounds__(256) void gat_attn(
    const float* __restrict__ fs,    // [B][F][512]
    const float* __restrict__ fd,
    const float* __restrict__ attn,  // [H][OW]
    float* __restrict__ ws2)         // [B][H][OW][F]
{
    __shared__ float A[OW], Bc[OW];
    __shared__ float pL[FF][FF];     // scores, then exp(scores - m)
    __shared__ float red[4][FF];
    __shared__ float red2[4][FF];
    __shared__ float invl[FF];

    const int b = blockIdx.x >> 2;
    const int h = blockIdx.x & 3;
    const int t = threadIdx.x;

    if (t < 32) {
        float4 av = *(const float4*)&attn[h * OW + t * 4];
        float4 a6, a4;
        a6.x = 0.6f * av.x; a6.y = 0.6f * av.y; a6.z = 0.6f * av.z; a6.w = 0.6f * av.w;
        a4.x = 0.4f * av.x; a4.y = 0.4f * av.y; a4.z = 0.4f * av.z; a4.w = 0.4f * av.w;
        *(float4*)&A[t * 4]  = a6;
        *(float4*)&Bc[t * 4] = a4;
    }
    __syncthreads();

    const float* fsb = fs + (size_t)b * FF * HO + h * OW;
    const float* fdb = fd + (size_t)b * FF * HO + h * OW;

    // ---- phase 1: scores, (4i x 4j) tile ----
    {
        const int i0 = (t >> 4) * 4;
        const int j0 = (t & 15) * 4;
        float sc[4][4] = {};
        #pragma unroll 2
        for (int c = 0; c < 32; ++c) {
            float4 fsv[4], fdv[4];
            #pragma unroll
            for (int m = 0; m < 4; ++m)
                fsv[m] = *(const float4*)&fsb[(size_t)(i0 + m) * HO + c * 4];
            #pragma unroll
            for (int n = 0; n < 4; ++n)
                fdv[n] = *(const float4*)&fdb[(size_t)(j0 + n) * HO + c * 4];
            float4 Av = *(const float4*)&A[c * 4];
            float4 Bv = *(const float4*)&Bc[c * 4];
            const float* Af = (const float*)&Av;
            const float* Bf = (const float*)&Bv;
            #pragma unroll
            for (int m = 0; m < 4; ++m) {
                const float* fsf = (const float*)&fsv[m];
                #pragma unroll
                for (int n = 0; n < 4; ++n) {
                    const float* fdf = (const float*)&fdv[n];
                    #pragma unroll
                    for (int dd = 0; dd < 4; ++dd) {
                        float s = fsf[dd] + fdf[dd];
                        sc[m][n] = fmaf(Af[dd], s, fmaf(Bf[dd], fabsf(s), sc[m][n]));
                    }
                }
            }
        }
        #pragma unroll
        for (int m = 0; m < 4; ++m) {
            float4 o; o.x = sc[m][0]; o.y = sc[m][1]; o.z = sc[m][2]; o.w = sc[m][3];
            *(float4*)&pL[i0 + m][j0] = o;
        }
    }
    __syncthreads();

    // ---- phase 2: softmax over i (columns), wave w owns rows [16w,16w+16) ----
    {
        const int w = t >> 6, l = t & 63;
        float pmax = -1e30f;
        #pragma unroll
        for (int i = 0; i < 16; ++i) pmax = fmaxf(pmax, pL[16 * w + i][l]);
        red[w][l] = pmax;
        __syncthreads();
        float mj = fmaxf(fmaxf(red[0][l], red[1][l]), fmaxf(red[2][l], red[3][l]));
        float psum = 0.0f;
        #pragma unroll
        for (int i = 0; i < 16; ++i) {
            float e = __expf(pL[16 * w + i][l] - mj);
            pL[16 * w + i][l] = e;
            psum += e;
        }
        red2[w][l] = psum;
        __syncthreads();
        // every wave computes the identical value; own-wave writes cover all j
        float lj = red2[0][l] + red2[1][l] + red2[2][l] + red2[3][l];
        invl[l] = 0.25f / lj;
    }
    __syncthreads();

    // ---- phase 3: aggregation, (4j x 8d) tile over i ----
    {
        const int j0 = (t & 15) * 4;
        const int d0 = (t >> 4) * 8;
        float ag[4][8] = {};
        #pragma unroll 2
        for (int i = 0; i < FF; ++i) {
            float4 pv = *(const float4*)&pL[i][j0];
            const float* fr = fsb + (size_t)i * HO + d0;
            float4 f0v = *(const float4*)fr;
            float4 f1v = *(const float4*)(fr + 4);
            const float* pf = (const float*)&pv;
            const float* ff0 = (const float*)&f0v;
            const float* ff1 = (const float*)&f1v;
            #pragma unroll
            for (int n = 0; n < 4; ++n) {
                #pragma unroll
                for (int dd = 0; dd < 4; ++dd) {
                    ag[n][dd]     = fmaf(pf[n], ff0[dd], ag[n][dd]);
                    ag[n][dd + 4] = fmaf(pf[n], ff1[dd], ag[n][dd + 4]);
                }
            }
        }
        float4 iv = *(const float4*)&invl[j0];
        const float* ivf = (const float*)&iv;
        #pragma unroll
        for (int dd = 0; dd < 8; ++dd) {
            float4 o;
            o.x = ag[0][dd] * ivf[0];
            o.y = ag[1][dd] * ivf[1];
            o.z = ag[2][dd] * ivf[2];
            o.w = ag[3][dd] * ivf[3];
            *(float4*)&ws2[(((size_t)b * HH + h) * OW + d0 + dd) * FF + j0] = o;
        }
    }
}

// ---------------------------------------------------------------------------
// Kernel 3: head-mean (0.25 already folded) + final store out[b][d][j].
// ---------------------------------------------------------------------------
__global__ __launch_bounds__(256) void gat_reduce(
    const float* __restrict__ ws2,   // [B][H][OW][F]
    float* __restrict__ out)         // [B][OW][F]
{
    const int g = blockIdx.x * 256 + threadIdx.x;     // float4 index, 131072 total
    const int b   = g >> 11;                          // 2048 float4 per batch
    const int rem = (g & 2047) * 4;                   // float offset within [OW][F]
    const float* base = ws2 + (size_t)b * (HH * OW * FF) + rem;
    float4 s0 = *(const float4*)(base);
    float4 s1 = *(const float4*)(base + OW * FF);
    float4 s2 = *(const float4*)(base + 2 * OW * FF);
    float4 s3 = *(const float4*)(base + 3 * OW * FF);
    float4 o;
    o.x = s0.x + s1.x + s2.x + s3.x;
    o.y = s0.y + s1.y + s2.y + s3.y;
    o.z = s0.z + s1.z + s2.z + s3.z;
    o.w = s0.w + s1.w + s2.w + s3.w;
    *(float4*)&out[(size_t)b * (OW * FF) + rem] = o;
}

// ---------------------------------------------------------------------------
extern "C" void kernel_launch(void* const* d_in, const int* in_sizes, int n_in,
                              void* d_out, int out_size, void* d_ws, size_t ws_size,
                              hipStream_t stream) {
    const float* x    = (const float*)d_in[0];
    const float* Wsrc = (const float*)d_in[1];
    const float* bsrc = (const float*)d_in[2];
    const float* Wdst = (const float*)d_in[3];
    const float* bdst = (const float*)d_in[4];
    const float* attn = (const float*)d_in[5];
    float* out = (float*)d_out;

    float* fs  = (float*)d_ws;                        // 8 MB
    float* fd  = fs  + (size_t)BB * FF * HO;          // 8 MB
    float* ws2 = fd  + (size_t)BB * FF * HO;          // 8 MB

    gat_proj  <<<BB * 16, 128, 0, stream>>>(x, Wsrc, bsrc, Wdst, bdst, fs, fd);
    gat_attn  <<<BB * HH, 256, 0, stream>>>(fs, fd, attn, ws2);
    gat_reduce<<<512,     256, 0, stream>>>(ws2, out);
}